// Round 8
// baseline (207.433 us; speedup 1.0000x reference)
//
#include <hip/hip_runtime.h>

// Problem: B=8, N=1024, C=512, H=8, dh=64.
// out = lin_bn_relu_p( relu( SCALE * Q @ (K^T V) ) ), Q/K/V = lin_bn_relu(x)
// (no softmax -> attention reassociates; K^T V is 64x64 per (b,h))
//
// ROUND 6 (3rd resubmit; R5/R6 GPU-acquisition timeouts, R7 container
// failure — all infra, kernel never measured): attn fused INTO gemm_p
// (BK=64 == one head: A-tile built on the fly as relu(0.125*Q_tile @ S[head])
// via MFMA, K=64). Removes the attn kernel, its 16 MB HBM round-trip, and one
// launch; fused gemm_p runs 512 blocks (2/CU). ktv -> atomicAdd into final
// 1 MB S (zeroed in prep).
// 4 launches: prep_all, gemm_qkv, ktv, gemm_p_fused.

#define CDIM  512
#define NSEQ  1024
#define MROWS 8192   // B*N

typedef __attribute__((ext_vector_type(8))) __bf16  bf16x8;
typedef __attribute__((ext_vector_type(4))) float   f32x4;
typedef __attribute__((ext_vector_type(8))) ushort  u16x8;

__device__ __forceinline__ float b2f(ushort u) {
    union { uint i; float f; } v; v.i = ((uint)u) << 16; return v.f;
}
__device__ __forceinline__ ushort f2b(float f) {
    union { float f; uint i; } v; v.f = f;
    uint u = v.i;
    u = u + 0x7fffu + ((u >> 16) & 1u);   // round-to-nearest-even
    return (ushort)(u >> 16);
}
__device__ __forceinline__ float ldv(const void* p, long i, int f32) {
    return f32 ? ((const float*)p)[i] : b2f(((const ushort*)p)[i]);
}

// async global->LDS, 16B per lane; LDS dest is wave-uniform base + lane*16
__device__ __forceinline__ void gload16(const void* g, void* l) {
    __builtin_amdgcn_global_load_lds(
        (const __attribute__((address_space(1))) void*)g,
        (__attribute__((address_space(3))) void*)l,
        16, 0, 0);
}

struct BnArgs {
    const void* b[4]; const void* g[4]; const void* be[4];
    const void* mu[4]; const void* va[4];
};
struct WPtrs { const void* w[4]; };

// ---------------------------------------------------------------------------
// Fused prep: grid 2824 blocks x 256.
//   [0,2048)    : conv x -> bf16 (8 elems/thread)
//   [2048,2560) : conv 4 weights -> bf16
//   [2560,2568) : fold BN into s/t
//   [2568,2824) : zero S (1 MB)
// Dtype detect is per-block (first 4 KB of x, L2-hot); block 0 publishes flag.
// ---------------------------------------------------------------------------
__global__ __launch_bounds__(256) void prep_all(
    const void* __restrict__ x, WPtrs wp, BnArgs bn,
    ushort* __restrict__ Xb, ushort* __restrict__ Wb,
    float* __restrict__ s_all, float* __restrict__ t_all,
    float* __restrict__ S, int* __restrict__ flag)
{
    const int blk = blockIdx.x, t = threadIdx.x;
    if (blk >= 2568) {   // zero S
        ((float4*)S)[(blk - 2568) * 256 + t] = make_float4(0.f, 0.f, 0.f, 0.f);
        return;
    }

    // ---- local dtype detect (bf16 N(0,1) never has exponent >= 0xC8) ----
    __shared__ int cnt;
    if (t == 0) cnt = 0;
    __syncthreads();
    {
        const ushort* xu = (const ushort*)x;
        int c = 0;
        for (int i = t; i < 2048; i += 256) {
            uint e = ((uint)xu[i] >> 7) & 0xffu;
            if (e >= 0xC8u) ++c;
        }
        if (c) atomicAdd(&cnt, c);
    }
    __syncthreads();
    const int f32 = cnt > 32;
    if (blk == 0 && t == 0) *flag = f32;

    if (blk < 2048) {            // ---- conv x ----
        long i = ((long)blk * 256 + t) * 8;
        if (f32) {
            const float* s = (const float*)x + i;
            u16x8 o;
            #pragma unroll
            for (int j = 0; j < 8; ++j) o[j] = f2b(s[j]);
            *(u16x8*)(Xb + i) = o;
        } else {
            *(u16x8*)(Xb + i) = *(const u16x8*)((const ushort*)x + i);
        }
    } else if (blk < 2560) {     // ---- conv weights ----
        int bb = blk - 2048;
        int p = bb >> 7;
        long i = ((long)(bb & 127) * 256 + t) * 8;
        const void* src = wp.w[p];
        ushort* d = Wb + (long)p * 262144 + i;
        if (f32) {
            const float* s = (const float*)src + i;
            u16x8 o;
            #pragma unroll
            for (int j = 0; j < 8; ++j) o[j] = f2b(s[j]);
            *(u16x8*)d = o;
        } else {
            *(u16x8*)d = *(const u16x8*)((const ushort*)src + i);
        }
    } else {                     // ---- fold BN ----
        int idx = (blk - 2560) * 256 + t;   // 0..2047
        int br = idx >> 9, c = idx & 511;
        float g  = ldv(bn.g[br],  c, f32);
        float be = ldv(bn.be[br], c, f32);
        float mu = ldv(bn.mu[br], c, f32);
        float va = ldv(bn.va[br], c, f32);
        float bb = ldv(bn.b[br],  c, f32);
        float s = g / sqrtf(va + 1e-5f);
        s_all[idx] = s;
        t_all[idx] = (bb - mu) * s + be;
    }
}

// ---------------------------------------------------------------------------
// Pipelined MFMA GEMM (unchanged from R5): O = relu((A @ Bw^T)*s + t).
// 128x128 tile, BK=64, double-buffered LDS, STAGE before compute, one
// barrier per K-step.
// ---------------------------------------------------------------------------
__device__ __forceinline__ void gemm128(
    const ushort* __restrict__ A, const ushort* __restrict__ Bw, void* __restrict__ O,
    const float* __restrict__ s_all, const float* __restrict__ t_all,
    int st_off, int of32)
{
    __shared__ ushort As[2][8192];   // [buf][128][64] bf16, 16 KB each
    __shared__ ushort Bs[2][8192];
    const int t = threadIdx.x;
    const int wave = t >> 6, lane = t & 63;
    const int wr = wave >> 1, wc = wave & 1;
    const long row0 = (long)blockIdx.x * 128;
    const int  col0 = blockIdx.y * 128;

    const ushort* gA = A  + (row0 + (t >> 3)) * CDIM + (t & 7) * 8;
    const ushort* gB = Bw + (long)(col0 + (t >> 3)) * CDIM + (t & 7) * 8;

    auto STAGE = [&](int b, int k0) {
        #pragma unroll
        for (int r = 0; r < 4; ++r) {
            gload16(gA + (long)r * 32 * CDIM + k0, &As[b][r * 2048 + wave * 512]);
            gload16(gB + (long)r * 32 * CDIM + k0, &Bs[b][r * 2048 + wave * 512]);
        }
    };

    f32x4 acc[4][4] = {};

    STAGE(0, 0);
    __syncthreads();

    #pragma unroll
    for (int kt = 0; kt < 8; ++kt) {
        const int cur = kt & 1;
        if (kt < 7) STAGE(cur ^ 1, (kt + 1) * 64);

        #pragma unroll
        for (int ks = 0; ks < 2; ++ks) {
            bf16x8 av[4], bv[4];
            #pragma unroll
            for (int m = 0; m < 4; ++m)
                av[m] = *(const bf16x8*)&As[cur][(wr * 64 + m * 16 + (lane & 15)) * 64 + ks * 32 + (lane >> 4) * 8];
            #pragma unroll
            for (int n = 0; n < 4; ++n)
                bv[n] = *(const bf16x8*)&Bs[cur][(wc * 64 + n * 16 + (lane & 15)) * 64 + ks * 32 + (lane >> 4) * 8];
            #pragma unroll
            for (int m = 0; m < 4; ++m)
                #pragma unroll
                for (int n = 0; n < 4; ++n)
                    acc[m][n] = __builtin_amdgcn_mfma_f32_16x16x32_bf16(av[m], bv[n], acc[m][n], 0, 0, 0);
        }
        __syncthreads();
    }

    const int lr4 = (lane >> 4) * 4, lc = lane & 15;
    #pragma unroll
    for (int n = 0; n < 4; ++n) {
        const int col = col0 + wc * 64 + n * 16 + lc;
        const float s = s_all[st_off + col], tt = t_all[st_off + col];
        #pragma unroll
        for (int m = 0; m < 4; ++m) {
            const long rb = row0 + wr * 64 + m * 16 + lr4;
            #pragma unroll
            for (int i = 0; i < 4; ++i) {
                float v = acc[m][n][i] * s + tt;
                v = v > 0.f ? v : 0.f;
                if (of32) ((float*)O)[(rb + i) * CDIM + col] = v;
                else      ((ushort*)O)[(rb + i) * CDIM + col] = f2b(v);
            }
        }
    }
}

// Fused Q/K/V: grid (64, 4, 3); z selects weight/output/st_off. bf16 out.
__global__ __launch_bounds__(256) void gemm_qkv(
    const ushort* __restrict__ Xb, const ushort* __restrict__ Wb,
    ushort* __restrict__ QKV,
    const float* __restrict__ s_all, const float* __restrict__ t_all)
{
    int z = blockIdx.z;
    gemm128(Xb, Wb + (long)z * 262144, QKV + (long)z * 4194304,
            s_all, t_all, z * 512, 0);
}

// ---------------------------------------------------------------------------
// S[bh][d1][d2] += sum_{n in slice} K[b,n,h*64+d1] * V[b,n,h*64+d2]
// grid (64 bh, 8 n-slices of 128); atomicAdd into zeroed S (low contention:
// each cell hit by exactly 8 blocks).
// ---------------------------------------------------------------------------
__global__ __launch_bounds__(256) void ktv_kernel(
    const ushort* __restrict__ K, const ushort* __restrict__ V,
    float* __restrict__ S)
{
    int bh = blockIdx.x, b = bh >> 3, h = bh & 7;
    int ns = blockIdx.y;
    __shared__ float Ks[32][64];
    __shared__ float Vs[32][64];
    int t = threadIdx.x;
    int lr = t >> 3, lc = (t & 7) * 8;
    int r0 = (t >> 4) * 4, c0 = (t & 15) * 4;
    const ushort* Kb = K + ((long)b * NSEQ + ns * 128) * CDIM + h * 64;
    const ushort* Vb = V + ((long)b * NSEQ + ns * 128) * CDIM + h * 64;

    float acc[4][4] = {};
    for (int it = 0; it < 4; ++it) {
        __syncthreads();
        long n = (long)(it * 32 + lr) * CDIM;
        u16x8 kv = *(const u16x8*)&Kb[n + lc];
        u16x8 vv = *(const u16x8*)&Vb[n + lc];
        #pragma unroll
        for (int j = 0; j < 8; ++j) {
            Ks[lr][lc + j] = b2f(kv[j]);
            Vs[lr][lc + j] = b2f(vv[j]);
        }
        __syncthreads();
        #pragma unroll
        for (int nn = 0; nn < 32; ++nn) {
            f32x4 kf = *(const f32x4*)&Ks[nn][r0];
            f32x4 vf = *(const f32x4*)&Vs[nn][c0];
            #pragma unroll
            for (int i = 0; i < 4; ++i)
                #pragma unroll
                for (int j = 0; j < 4; ++j)
                    acc[i][j] += kf[i] * vf[j];
        }
    }
    float* out = S + (long)bh * 4096 + r0 * 64 + c0;
    #pragma unroll
    for (int i = 0; i < 4; ++i)
        #pragma unroll
        for (int j = 0; j < 4; ++j)
            atomicAdd(&out[i * 64 + j], acc[i][j]);
}

// ---------------------------------------------------------------------------
// FUSED attn + final projection. Per block: 64 rows x 128 out-cols.
// K-step kt == head kt: A-tile[64][64] = relu( Q[rows, head kt] @ (0.125*S[b,kt]) )
// built via MFMA (K=64) from LDS-staged Q-tile and bf16 S^T, then consumed by
// the main MFMA against Wp. Grid (128,4) = 512 blocks = 2/CU. 2 barriers/kt.
// ---------------------------------------------------------------------------
__global__ __launch_bounds__(256) void gemm_p_fused(
    const ushort* __restrict__ Q, const ushort* __restrict__ Wp,
    const float* __restrict__ S, void* __restrict__ O,
    const float* __restrict__ s_all, const float* __restrict__ t_all,
    const int* __restrict__ flag)
{
    __shared__ ushort Qs[2][4096];    // [64 rows][64 k] bf16, dbuf
    __shared__ ushort Bs[2][8192];    // [128 cols][64 k] bf16, dbuf
    __shared__ ushort St[2][4608];    // [64 d2][72 d1] bf16 (stride 72: 16B-aligned rows), dbuf
    __shared__ ushort As[4096];       // [64 rows][64 k] attn-out tile, single buf
    const int t = threadIdx.x, wave = t >> 6, lane = t & 63;
    const int wr = wave >> 1, wc = wave & 1;
    const long row0 = (long)blockIdx.x * 64;
    const int  col0 = blockIdx.y * 128;
    const int  b8   = (blockIdx.x >> 4) * 8;   // batch*8 (16 row-blocks per batch)
    const int  of32 = *flag;

    const ushort* gQ = Q  + (row0 + (t >> 3)) * CDIM + (t & 7) * 8;
    const ushort* gW = Wp + (long)(col0 + (t >> 3)) * CDIM + (t & 7) * 8;

    auto STAGE_Q = [&](int bf, int kt) {   // 64x64 bf16 = 8 KB, 2 gload16/thread
        #pragma unroll
        for (int r = 0; r < 2; ++r)
            gload16(gQ + (long)r * 32 * CDIM + kt * 64, &Qs[bf][r * 2048 + wave * 512]);
    };
    auto STAGE_W = [&](int bf, int kt) {   // 128x64 bf16 = 16 KB, 4 gload16/thread
        #pragma unroll
        for (int r = 0; r < 4; ++r)
            gload16(gW + (long)r * 32 * CDIM + kt * 64, &Bs[bf][r * 2048 + wave * 512]);
    };
    auto STAGE_S = [&](int bf, int kt) {   // S[b,kt] f32 -> bf16(0.125*S)^T
        const float* Sp = S + (long)(b8 + kt) * 4096;
        #pragma unroll
        for (int j = 0; j < 16; ++j) {
            int e = j * 256 + t;           // d1 = e>>6, d2 = e&63 (coalesced read)
            St[bf][(e & 63) * 72 + (e >> 6)] = f2b(0.125f * Sp[e]);
        }
    };

    f32x4 acc[2][4] = {};

    STAGE_Q(0, 0); STAGE_W(0, 0); STAGE_S(0, 0);
    __syncthreads();

    for (int kt = 0; kt < 8; ++kt) {
        const int cur = kt & 1;
        if (kt < 7) { STAGE_Q(cur ^ 1, kt + 1); STAGE_W(cur ^ 1, kt + 1); STAGE_S(cur ^ 1, kt + 1); }

        // ---- attn MFMA: wave w computes rows [w*16, w*16+16) x all 64 d2 ----
        f32x4 p[4] = {};
        #pragma unroll
        for (int ks = 0; ks < 2; ++ks) {
            bf16x8 aq = *(const bf16x8*)&Qs[cur][(wave * 16 + (lane & 15)) * 64 + ks * 32 + (lane >> 4) * 8];
            #pragma unroll
            for (int n = 0; n < 4; ++n) {
                bf16x8 bs = *(const bf16x8*)&St[cur][(n * 16 + (lane & 15)) * 72 + ks * 32 + (lane >> 4) * 8];
                p[n] = __builtin_amdgcn_mfma_f32_16x16x32_bf16(aq, bs, p[n], 0, 0, 0);
            }
        }
        __syncthreads();   // all waves done reading As of kt-1

        {   // relu + bf16 + scatter to As  (C/D layout: col=lane&15, row=(lane>>4)*4+i)
            const int rb = wave * 16 + (lane >> 4) * 4, cb = lane & 15;
            #pragma unroll
            for (int n = 0; n < 4; ++n)
                #pragma unroll
                for (int i = 0; i < 4; ++i) {
                    float v = p[n][i];
                    As[(rb + i) * 64 + n * 16 + cb] = f2b(v > 0.f ? v : 0.f);
                }
        }
        __syncthreads();   // As ready; drains prefetch vmcnt + St ds_writes

        // ---- main MFMA: acc += As(rows) x Wp-tile ----
        #pragma unroll
        for (int ks = 0; ks < 2; ++ks) {
            bf16x8 av[2], bv[4];
            #pragma unroll
            for (int m = 0; m < 2; ++m)
                av[m] = *(const bf16x8*)&As[(wr * 32 + m * 16 + (lane & 15)) * 64 + ks * 32 + (lane >> 4) * 8];
            #pragma unroll
            for (int n = 0; n < 4; ++n)
                bv[n] = *(const bf16x8*)&Bs[cur][(wc * 64 + n * 16 + (lane & 15)) * 64 + ks * 32 + (lane >> 4) * 8];
            #pragma unroll
            for (int m = 0; m < 2; ++m)
                #pragma unroll
                for (int n = 0; n < 4; ++n)
                    acc[m][n] = __builtin_amdgcn_mfma_f32_16x16x32_bf16(av[m], bv[n], acc[m][n], 0, 0, 0);
        }
    }

    // epilogue: bn + relu + store (wave tile 32x64 within 64x128 block tile)
    const int lr4 = (lane >> 4) * 4, lc = lane & 15;
    #pragma unroll
    for (int n = 0; n < 4; ++n) {
        const int col = col0 + wc * 64 + n * 16 + lc;
        const float s = s_all[1536 + col], tt = t_all[1536 + col];
        #pragma unroll
        for (int m = 0; m < 2; ++m) {
            const long rb = row0 + wr * 32 + m * 16 + lr4;
            #pragma unroll
            for (int i = 0; i < 4; ++i) {
                float v = acc[m][n][i] * s + tt;
                v = v > 0.f ? v : 0.f;
                if (of32) ((float*)O)[(rb + i) * CDIM + col] = v;
                else      ((ushort*)O)[(rb + i) * CDIM + col] = f2b(v);
            }
        }
    }
}

// ---------------------------------------------------------------------------
extern "C" void kernel_launch(void* const* d_in, const int* in_sizes, int n_in,
                              void* d_out, int out_size, void* d_ws, size_t ws_size,
                              hipStream_t stream)
{
    const void* x = d_in[0];
    WPtrs wp; BnArgs bn;
    for (int p = 0; p < 4; ++p) {
        wp.w[p]   = d_in[1 + 6 * p + 0];
        bn.b[p]   = d_in[1 + 6 * p + 1];
        bn.g[p]   = d_in[1 + 6 * p + 2];
        bn.be[p]  = d_in[1 + 6 * p + 3];
        bn.mu[p]  = d_in[1 + 6 * p + 4];
        bn.va[p]  = d_in[1 + 6 * p + 5];
    }

    // workspace layout (~27.3 MB); x_bf16 lives in d_out (dead until gemm_p)
    char* ws = (char*)d_ws;
    float*  s_all = (float*)ws;                          // 8 KB
    float*  t_all = (float*)(ws + 8192);                 // 8 KB
    int*    flag  = (int*)(ws + 16384);                  // 256 B reserved
    ushort* Wb    = (ushort*)(ws + 16640);               // 4x512x512 bf16 = 2 MB
    ushort* QKV   = (ushort*)(ws + 16640 + 2097152);     // 3 x 8 MB bf16
    float*  S     = (float*)(ws + 16640 + 2097152 + 3L * 8388608);  // 1 MB fp32
    ushort* Xb    = (ushort*)d_out;                      // 8 MB bf16 scratch

    // 1) all prep in one launch (conv x, conv w, fold BN, zero S, publish flag)
    prep_all<<<2824, 256, 0, stream>>>(x, wp, bn, Xb, Wb, s_all, t_all, S, flag);

    // 2) Q/K/V = relu(bn(x @ w^T)) — fused, 768 blocks
    gemm_qkv<<<dim3(64, 4, 3), 256, 0, stream>>>(Xb, Wb, QKV, s_all, t_all);

    // 3) S = K^T V per (b,h), 8-way n-split, atomics into zeroed S
    ktv_kernel<<<dim3(64, 8), 256, 0, stream>>>(QKV + 4194304, QKV + 2L * 4194304, S);

    // 4) out = relu(bn( relu(0.125 * Q @ S) @ p_w^T ))  — attn fused in
    gemm_p_fused<<<dim3(128, 4), 256, 0, stream>>>(QKV, Wb + 3L * 262144, S, d_out,
                                                   s_all, t_all, flag);
}

// Round 10
// 176.327 us; speedup vs baseline: 1.1764x; 1.1764x over previous
//
#include <hip/hip_runtime.h>

// Problem: B=8, N=1024, C=512, H=8, dh=64.
// out = lin_bn_relu_p( relu( SCALE * Q @ (K^T V) ) ), Q/K/V = lin_bn_relu(x)
// (no softmax -> attention reassociates; K^T V is 64x64 per (b,h))
//
// ROUND 9 (resubmit after GPU-acquisition timeout): REVERT R8 fusion (207 vs
// 187 — barrier-vmcnt drain exposed HBM latency twice per kt). Back to R4
// 5-kernel structure; new lever = occupancy: BK=32 dbuf pipeline (32 KB LDS)
// -> gemm_qkv 3 blocks/CU (no 512+256 tail), gemm_p on 64x128 tile (24 KB)
// -> 512 blocks = 2/CU cross-block overlap.
// 5 launches: prep_all, gemm_qkv, ktv, attn, gemm_p.

#define CDIM  512
#define NSEQ  1024
#define MROWS 8192   // B*N

typedef __attribute__((ext_vector_type(8))) __bf16  bf16x8;
typedef __attribute__((ext_vector_type(4))) float   f32x4;
typedef __attribute__((ext_vector_type(8))) ushort  u16x8;

__device__ __forceinline__ float b2f(ushort u) {
    union { uint i; float f; } v; v.i = ((uint)u) << 16; return v.f;
}
__device__ __forceinline__ ushort f2b(float f) {
    union { float f; uint i; } v; v.f = f;
    uint u = v.i;
    u = u + 0x7fffu + ((u >> 16) & 1u);   // round-to-nearest-even
    return (ushort)(u >> 16);
}
__device__ __forceinline__ float ldv(const void* p, long i, int f32) {
    return f32 ? ((const float*)p)[i] : b2f(((const ushort*)p)[i]);
}

// async global->LDS, 16B per lane; LDS dest is wave-uniform base + lane*16
__device__ __forceinline__ void gload16(const void* g, void* l) {
    __builtin_amdgcn_global_load_lds(
        (const __attribute__((address_space(1))) void*)g,
        (__attribute__((address_space(3))) void*)l,
        16, 0, 0);
}

struct BnArgs {
    const void* b[4]; const void* g[4]; const void* be[4];
    const void* mu[4]; const void* va[4];
};
struct WPtrs { const void* w[4]; };

// ---------------------------------------------------------------------------
// Fused prep: grid 2568 blocks x 256.
//   [0,2048)    : conv x -> bf16 (8 elems/thread)
//   [2048,2560) : conv 4 weights -> bf16
//   [2560,2568) : fold BN into s/t
// Dtype detect is per-block (first 4 KB of x, L2-hot); block 0 publishes flag.
// ---------------------------------------------------------------------------
__global__ __launch_bounds__(256) void prep_all(
    const void* __restrict__ x, WPtrs wp, BnArgs bn,
    ushort* __restrict__ Xb, ushort* __restrict__ Wb,
    float* __restrict__ s_all, float* __restrict__ t_all,
    int* __restrict__ flag)
{
    const int blk = blockIdx.x, t = threadIdx.x;

    // ---- local dtype detect (bf16 N(0,1) never has exponent >= 0xC8) ----
    __shared__ int cnt;
    if (t == 0) cnt = 0;
    __syncthreads();
    {
        const ushort* xu = (const ushort*)x;
        int c = 0;
        for (int i = t; i < 2048; i += 256) {
            uint e = ((uint)xu[i] >> 7) & 0xffu;
            if (e >= 0xC8u) ++c;
        }
        if (c) atomicAdd(&cnt, c);
    }
    __syncthreads();
    const int f32 = cnt > 32;
    if (blk == 0 && t == 0) *flag = f32;

    if (blk < 2048) {            // ---- conv x ----
        long i = ((long)blk * 256 + t) * 8;
        if (f32) {
            const float* s = (const float*)x + i;
            u16x8 o;
            #pragma unroll
            for (int j = 0; j < 8; ++j) o[j] = f2b(s[j]);
            *(u16x8*)(Xb + i) = o;
        } else {
            *(u16x8*)(Xb + i) = *(const u16x8*)((const ushort*)x + i);
        }
    } else if (blk < 2560) {     // ---- conv weights ----
        int bb = blk - 2048;
        int p = bb >> 7;
        long i = ((long)(bb & 127) * 256 + t) * 8;
        const void* src = wp.w[p];
        ushort* d = Wb + (long)p * 262144 + i;
        if (f32) {
            const float* s = (const float*)src + i;
            u16x8 o;
            #pragma unroll
            for (int j = 0; j < 8; ++j) o[j] = f2b(s[j]);
            *(u16x8*)d = o;
        } else {
            *(u16x8*)d = *(const u16x8*)((const ushort*)src + i);
        }
    } else {                     // ---- fold BN ----
        int idx = (blk - 2560) * 256 + t;   // 0..2047
        int br = idx >> 9, c = idx & 511;
        float g  = ldv(bn.g[br],  c, f32);
        float be = ldv(bn.be[br], c, f32);
        float mu = ldv(bn.mu[br], c, f32);
        float va = ldv(bn.va[br], c, f32);
        float bb = ldv(bn.b[br],  c, f32);
        float s = g / sqrtf(va + 1e-5f);
        s_all[idx] = s;
        t_all[idx] = (bb - mu) * s + be;
    }
}

// ---------------------------------------------------------------------------
// Pipelined MFMA GEMM, 128x128 tile, BK=32, dbuf (32 KB LDS -> 3 blocks/CU
// at 768-block grid: no scheduling tail, 12 waves/CU hide the per-step
// barrier vmcnt drain). One barrier per K-step, STAGE issued before compute.
// ---------------------------------------------------------------------------
__device__ __forceinline__ void gemm128(
    const ushort* __restrict__ A, const ushort* __restrict__ Bw, void* __restrict__ O,
    const float* __restrict__ s_all, const float* __restrict__ t_all,
    int st_off, int of32)
{
    __shared__ ushort As[2][4096];   // [buf][128][32] bf16, 8 KB each
    __shared__ ushort Bs[2][4096];
    const int t = threadIdx.x;
    const int wave = t >> 6, lane = t & 63;
    const int wr = wave >> 1, wc = wave & 1;
    const long row0 = (long)blockIdx.x * 128;
    const int  col0 = blockIdx.y * 128;

    // staging: round r covers rows r*64..r*64+63; thread t: row t>>2,
    // col chunk (t&3)*8. LDS linear in t (16 B/thread).
    const ushort* gA = A  + (row0 + (t >> 2)) * CDIM + (t & 3) * 8;
    const ushort* gB = Bw + (long)(col0 + (t >> 2)) * CDIM + (t & 3) * 8;

    auto STAGE = [&](int b, int k0) {
        #pragma unroll
        for (int r = 0; r < 2; ++r) {
            gload16(gA + (long)r * 64 * CDIM + k0, &As[b][r * 2048 + wave * 512]);
            gload16(gB + (long)r * 64 * CDIM + k0, &Bs[b][r * 2048 + wave * 512]);
        }
    };

    f32x4 acc[4][4] = {};

    STAGE(0, 0);
    __syncthreads();   // prologue drain; all waves see buf 0

    #pragma unroll
    for (int kt = 0; kt < 16; ++kt) {
        const int cur = kt & 1;
        if (kt < 15) STAGE(cur ^ 1, (kt + 1) * 32);   // prefetch next tile

        bf16x8 av[4], bv[4];
        #pragma unroll
        for (int m = 0; m < 4; ++m)
            av[m] = *(const bf16x8*)&As[cur][(wr * 64 + m * 16 + (lane & 15)) * 32 + (lane >> 4) * 8];
        #pragma unroll
        for (int n = 0; n < 4; ++n)
            bv[n] = *(const bf16x8*)&Bs[cur][(wc * 64 + n * 16 + (lane & 15)) * 32 + (lane >> 4) * 8];
        #pragma unroll
        for (int m = 0; m < 4; ++m)
            #pragma unroll
            for (int n = 0; n < 4; ++n)
                acc[m][n] = __builtin_amdgcn_mfma_f32_16x16x32_bf16(av[m], bv[n], acc[m][n], 0, 0, 0);
        __syncthreads();   // one barrier/K-step
    }

    // epilogue: C/D layout col=lane&15, row=(lane>>4)*4+reg  [m89-verified]
    const int lr4 = (lane >> 4) * 4, lc = lane & 15;
    #pragma unroll
    for (int n = 0; n < 4; ++n) {
        const int col = col0 + wc * 64 + n * 16 + lc;
        const float s = s_all[st_off + col], tt = t_all[st_off + col];
        #pragma unroll
        for (int m = 0; m < 4; ++m) {
            const long rb = row0 + wr * 64 + m * 16 + lr4;
            #pragma unroll
            for (int i = 0; i < 4; ++i) {
                float v = acc[m][n][i] * s + tt;
                v = v > 0.f ? v : 0.f;
                if (of32) ((float*)O)[(rb + i) * CDIM + col] = v;
                else      ((ushort*)O)[(rb + i) * CDIM + col] = f2b(v);
            }
        }
    }
}

// Fused Q/K/V: grid (64, 4, 3); z selects weight/output/st_off. bf16 out.
__global__ __launch_bounds__(256) void gemm_qkv(
    const ushort* __restrict__ Xb, const ushort* __restrict__ Wb,
    ushort* __restrict__ QKV,
    const float* __restrict__ s_all, const float* __restrict__ t_all)
{
    int z = blockIdx.z;
    gemm128(Xb, Wb + (long)z * 262144, QKV + (long)z * 4194304,
            s_all, t_all, z * 512, 0);
}

// ---------------------------------------------------------------------------
// Final projection on a 64x128 tile (BK=32 dbuf, 24 KB LDS): grid (128,4) =
// 512 blocks = 2 blocks/CU -> cross-block overlap that the old 256-block
// (1/CU) version lacked. B-panel re-reads are L2/L3-resident (0.5 MB weight).
// ---------------------------------------------------------------------------
__global__ __launch_bounds__(256) void gemm_p(
    const ushort* __restrict__ Aq, const ushort* __restrict__ Wp,
    void* __restrict__ O,
    const float* __restrict__ s_all, const float* __restrict__ t_all,
    const int* __restrict__ flag)
{
    __shared__ ushort As[2][2048];   // [buf][64][32] bf16, 4 KB each
    __shared__ ushort Bs[2][4096];   // [buf][128][32] bf16, 8 KB each
    const int t = threadIdx.x;
    const int wave = t >> 6, lane = t & 63;
    const int wr = wave >> 1, wc = wave & 1;
    const long row0 = (long)blockIdx.x * 64;
    const int  col0 = blockIdx.y * 128;
    const int  of32 = *flag;

    const ushort* gA = Aq + (row0 + (t >> 2)) * CDIM + (t & 3) * 8;
    const ushort* gB = Wp + (long)(col0 + (t >> 2)) * CDIM + (t & 3) * 8;

    auto STAGE = [&](int b, int k0) {
        gload16(gA + k0, &As[b][wave * 512]);   // 64 rows in one round
        #pragma unroll
        for (int r = 0; r < 2; ++r)
            gload16(gB + (long)r * 64 * CDIM + k0, &Bs[b][r * 2048 + wave * 512]);
    };

    f32x4 acc[2][4] = {};

    STAGE(0, 0);
    __syncthreads();

    #pragma unroll
    for (int kt = 0; kt < 16; ++kt) {
        const int cur = kt & 1;
        if (kt < 15) STAGE(cur ^ 1, (kt + 1) * 32);

        bf16x8 av[2], bv[4];
        #pragma unroll
        for (int m = 0; m < 2; ++m)
            av[m] = *(const bf16x8*)&As[cur][(wr * 32 + m * 16 + (lane & 15)) * 32 + (lane >> 4) * 8];
        #pragma unroll
        for (int n = 0; n < 4; ++n)
            bv[n] = *(const bf16x8*)&Bs[cur][(wc * 64 + n * 16 + (lane & 15)) * 32 + (lane >> 4) * 8];
        #pragma unroll
        for (int m = 0; m < 2; ++m)
            #pragma unroll
            for (int n = 0; n < 4; ++n)
                acc[m][n] = __builtin_amdgcn_mfma_f32_16x16x32_bf16(av[m], bv[n], acc[m][n], 0, 0, 0);
        __syncthreads();
    }

    const int lr4 = (lane >> 4) * 4, lc = lane & 15;
    #pragma unroll
    for (int n = 0; n < 4; ++n) {
        const int col = col0 + wc * 64 + n * 16 + lc;
        const float s = s_all[1536 + col], tt = t_all[1536 + col];
        #pragma unroll
        for (int m = 0; m < 2; ++m) {
            const long rb = row0 + wr * 32 + m * 16 + lr4;
            #pragma unroll
            for (int i = 0; i < 4; ++i) {
                float v = acc[m][n][i] * s + tt;
                v = v > 0.f ? v : 0.f;
                if (of32) ((float*)O)[(rb + i) * CDIM + col] = v;
                else      ((ushort*)O)[(rb + i) * CDIM + col] = f2b(v);
            }
        }
    }
}

// ---------------------------------------------------------------------------
// Spart[bh][ns][d1][d2] = sum_{n in slice ns} K[b,n,h*64+d1] * V[b,n,h*64+d2]
// grid (64 bh, 8 n-slices of 128); NON-atomic partials (attn reduces the 8).
// ---------------------------------------------------------------------------
__global__ __launch_bounds__(256) void ktv_kernel(
    const ushort* __restrict__ K, const ushort* __restrict__ V,
    float* __restrict__ Spart)
{
    int bh = blockIdx.x, b = bh >> 3, h = bh & 7;
    int ns = blockIdx.y;
    __shared__ float Ks[32][64];
    __shared__ float Vs[32][64];
    int t = threadIdx.x;
    int lr = t >> 3, lc = (t & 7) * 8;
    int r0 = (t >> 4) * 4, c0 = (t & 15) * 4;
    const ushort* Kb = K + ((long)b * NSEQ + ns * 128) * CDIM + h * 64;
    const ushort* Vb = V + ((long)b * NSEQ + ns * 128) * CDIM + h * 64;

    float acc[4][4] = {};
    for (int it = 0; it < 4; ++it) {
        __syncthreads();
        long n = (long)(it * 32 + lr) * CDIM;
        u16x8 kv = *(const u16x8*)&Kb[n + lc];
        u16x8 vv = *(const u16x8*)&Vb[n + lc];
        #pragma unroll
        for (int j = 0; j < 8; ++j) {
            Ks[lr][lc + j] = b2f(kv[j]);
            Vs[lr][lc + j] = b2f(vv[j]);
        }
        __syncthreads();
        #pragma unroll
        for (int nn = 0; nn < 32; ++nn) {
            f32x4 kf = *(const f32x4*)&Ks[nn][r0];
            f32x4 vf = *(const f32x4*)&Vs[nn][c0];
            #pragma unroll
            for (int i = 0; i < 4; ++i)
                #pragma unroll
                for (int j = 0; j < 4; ++j)
                    acc[i][j] += kf[i] * vf[j];
        }
    }
    float* out = Spart + ((long)bh * 8 + ns) * 4096 + r0 * 64 + c0;
    #pragma unroll
    for (int i = 0; i < 4; ++i)
        #pragma unroll
        for (int j = 0; j < 4; ++j)
            out[i * 64 + j] = acc[i][j];
}

// ---------------------------------------------------------------------------
// In-place attention: Q[b, m, h*64+d2] <- relu(0.125 * sum_d1 Q[..d1]*S[d1][d2])
// S materialized here by summing the 8 ktv partials during staging.
// Q tile staged TRANSPOSED in LDS -> inner loop is two float4 LDS reads.
// ---------------------------------------------------------------------------
__global__ __launch_bounds__(256) void attn_kernel(
    ushort* __restrict__ Q, const float* __restrict__ Spart)
{
    int bh = blockIdx.x, b = bh >> 3, h = bh & 7;
    int m0 = blockIdx.y * 64;
    __shared__ float Ss[64][64];   // [d1][d2]
    __shared__ float Qs[64][68];   // TRANSPOSED: [d1][row], pad 68
    int t = threadIdx.x, ty = t >> 4, tx = t & 15;

    for (int e = t; e < 4096; e += 256) {
        const float* sp = Spart + (long)bh * 32768 + e;
        float v = 0.f;
        #pragma unroll
        for (int ns = 0; ns < 8; ++ns) v += sp[ns * 4096];
        Ss[e >> 6][e & 63] = v;
    }
    ushort* Qb = Q + ((long)(b * NSEQ + m0)) * CDIM + h * 64;
    for (int e = t; e < 4096; e += 256) {
        int r = e >> 6, c = e & 63;
        Qs[c][r] = b2f(Qb[(long)r * CDIM + c]);
    }
    __syncthreads();

    float acc[4][4] = {};
    for (int d1 = 0; d1 < 64; ++d1) {
        f32x4 qv = *(const f32x4*)&Qs[d1][ty * 4];
        f32x4 sv = *(const f32x4*)&Ss[d1][tx * 4];
        #pragma unroll
        for (int i = 0; i < 4; ++i)
            #pragma unroll
            for (int j = 0; j < 4; ++j)
                acc[i][j] += qv[i] * sv[j];
    }
    #pragma unroll
    for (int i = 0; i < 4; ++i) {
        ushort4 o;
        o.x = f2b(fmaxf(0.125f * acc[i][0], 0.f));
        o.y = f2b(fmaxf(0.125f * acc[i][1], 0.f));
        o.z = f2b(fmaxf(0.125f * acc[i][2], 0.f));
        o.w = f2b(fmaxf(0.125f * acc[i][3], 0.f));
        *(ushort4*)&Qb[(long)(ty * 4 + i) * CDIM + tx * 4] = o;
    }
}

// ---------------------------------------------------------------------------
extern "C" void kernel_launch(void* const* d_in, const int* in_sizes, int n_in,
                              void* d_out, int out_size, void* d_ws, size_t ws_size,
                              hipStream_t stream)
{
    const void* x = d_in[0];
    WPtrs wp; BnArgs bn;
    for (int p = 0; p < 4; ++p) {
        wp.w[p]   = d_in[1 + 6 * p + 0];
        bn.b[p]   = d_in[1 + 6 * p + 1];
        bn.g[p]   = d_in[1 + 6 * p + 2];
        bn.be[p]  = d_in[1 + 6 * p + 3];
        bn.mu[p]  = d_in[1 + 6 * p + 4];
        bn.va[p]  = d_in[1 + 6 * p + 5];
    }

    // workspace layout (~34.7 MB); x_bf16 lives in d_out (dead until gemm_p)
    char* ws = (char*)d_ws;
    float*  s_all = (float*)ws;                          // 8 KB
    float*  t_all = (float*)(ws + 8192);                 // 8 KB
    int*    flag  = (int*)(ws + 16384);                  // 256 B reserved
    ushort* Wb    = (ushort*)(ws + 16640);               // 4x512x512 bf16 = 2 MB
    ushort* QKV   = (ushort*)(ws + 16640 + 2097152);     // 3 x 8 MB bf16
    float*  Spart = (float*)(ws + 16640 + 2097152 + 3L * 8388608);  // 8.39 MB fp32
    ushort* Xb    = (ushort*)d_out;                      // 8 MB bf16 scratch

    // 1) all prep in one launch (conv x, conv w, fold BN, publish flag)
    prep_all<<<2568, 256, 0, stream>>>(x, wp, bn, Xb, Wb, s_all, t_all, flag);

    // 2) Q/K/V = relu(bn(x @ w^T)) — fused, 768 blocks, 3/CU co-resident
    gemm_qkv<<<dim3(64, 4, 3), 256, 0, stream>>>(Xb, Wb, QKV, s_all, t_all);

    // 3) Spart = per-slice K^T V per (b,h), no atomics
    ktv_kernel<<<dim3(64, 8), 256, 0, stream>>>(QKV + 4194304, QKV + 2L * 4194304, Spart);

    // 4) Q <- relu(SCALE * Q @ sum(Spart))   (in place)
    attn_kernel<<<dim3(64, 16), 256, 0, stream>>>(QKV, Spart);

    // 5) out = relu(bn(attn_out @ p_w^T)) — 512 blocks, 2/CU
    gemm_p<<<dim3(128, 4), 256, 0, stream>>>(QKV, Wb + 3L * 262144, d_out,
                                             s_all, t_all, flag);
}